// Round 5
// baseline (331.334 us; speedup 1.0000x reference)
//
#include <hip/hip_runtime.h>

// x: [B=2, C=3, D=128, H=160, W=160] fp32, num_steps=6
#define BB 2
#define DD 128
#define HH 160
#define WW 160
constexpr int S   = DD * HH * WW;   // voxels per batch   = 3,276,800
constexpr int PL  = HH * WW;        // plane (h*w)        = 25,600
constexpr int VPB = 512;            // voxels per block (2 per thread)
constexpr int BPP = PL / VPB;       // 50 blocks per plane
constexpr int NBLK = BB * DD * BPP; // 12800 blocks
constexpr int PER_XCD = NBLK / 8;   // contiguous 32-plane slab per XCD

struct I3 { int d, h, w; };
struct F3 { float x, y, z; };

__device__ __forceinline__ I3 warp_coords(int d, int h, int w, F3 f) {
    // round-half-to-even (jnp.round == rintf), clamp per-dim
    I3 r;
    r.d = (int)fminf(fmaxf(rintf((float)d + f.x), 0.0f), (float)(DD - 1));
    r.h = (int)fminf(fmaxf(rintf((float)h + f.y), 0.0f), (float)(HH - 1));
    r.w = (int)fminf(fmaxf(rintf((float)w + f.z), 0.0f), (float)(WW - 1));
    return r;
}

// packed 12B load/store -> single global_load_dwordx3 / store_dwordx3
__device__ __forceinline__ F3 ld3(const float* p) {
    F3 r; __builtin_memcpy(&r, p, 12); return r;
}
__device__ __forceinline__ void st3(float* p, F3 v) {
    __builtin_memcpy(p, &v, 12);
}

// ---- fused steps 1..3, reading SoA x with the 1/64 scale folded in ----
__device__ __forceinline__ F3 ld_soa(const float* __restrict__ xb, int d, int h, int w) {
    const float scale = 1.0f / 64.0f;
    int i = (d * HH + h) * WW + w;
    F3 r; r.x = xb[i] * scale; r.y = xb[i + S] * scale; r.z = xb[i + 2 * S] * scale;
    return r;
}

__device__ __forceinline__ F3 v1_at(const float* __restrict__ xb, int d, int h, int w) {
    F3 f = ld_soa(xb, d, h, w);
    I3 q = warp_coords(d, h, w, f);
    F3 g = ld_soa(xb, q.d, q.h, q.w);
    return {f.x + g.x, f.y + g.y, f.z + g.z};   // exact unfused pass-1 arithmetic
}

__device__ __forceinline__ F3 v2_at(const float* __restrict__ xb, int d, int h, int w) {
    F3 a = v1_at(xb, d, h, w);
    I3 r = warp_coords(d, h, w, a);
    F3 b = v1_at(xb, r.d, r.h, r.w);
    return {a.x + b.x, a.y + b.y, a.z + b.z};   // exact unfused pass-2 arithmetic
}

__device__ __forceinline__ F3 v3_at(const float* __restrict__ xb, int d, int h, int w) {
    F3 a = v2_at(xb, d, h, w);
    I3 r = warp_coords(d, h, w, a);
    F3 b = v2_at(xb, r.d, r.h, r.w);
    return {a.x + b.x, a.y + b.y, a.z + b.z};   // exact unfused pass-3 arithmetic
}

__global__ __launch_bounds__(256) void fused3_k(const float* __restrict__ x,
                                                float* __restrict__ vout) {
    // XCD-aware swizzle: each XCD owns a contiguous 32-plane slab.
    int bid = blockIdx.x;
    int nb  = (bid >> 3) + (bid & 7) * PER_XCD;
    int b   = nb / (DD * BPP);
    int rr  = nb - b * (DD * BPP);
    int d   = rr / BPP;
    int ip0 = (rr - d * BPP) * VPB + threadIdx.x;
    const float* xb = x + b * 3 * S;

    for (int v = 0; v < 2; ++v) {
        int ip = ip0 + v * 256;
        int w = ip % WW, h = ip / WW;
        F3 o = v3_at(xb, d, h, w);
        st3(vout + (size_t)(b * S + d * PL + ip) * 3, o);
    }
}

// ---- unfused step (AoS in, AoS or SoA out), 2 voxels/thread with MLP ----
template <bool OUT_SOA>
__global__ __launch_bounds__(256) void step_k(const float* __restrict__ vin,
                                              float* __restrict__ vout) {
    int bid = blockIdx.x;
    int nb  = (bid >> 3) + (bid & 7) * PER_XCD;
    int b   = nb / (DD * BPP);
    int rr  = nb - b * (DD * BPP);
    int d   = rr / BPP;
    int ip0 = (rr - d * BPP) * VPB + threadIdx.x;
    int ip1 = ip0 + 256;
    int w0 = ip0 % WW, h0 = ip0 / WW;
    int w1 = ip1 % WW, h1 = ip1 / WW;
    int p0 = d * PL + ip0, p1 = d * PL + ip1;

    // both centers first (independent), then both gathers (independent)
    F3 f0 = ld3(vin + (size_t)(b * S + p0) * 3);
    F3 f1 = ld3(vin + (size_t)(b * S + p1) * 3);
    I3 q0 = warp_coords(d, h0, w0, f0);
    I3 q1 = warp_coords(d, h1, w1, f1);
    F3 g0 = ld3(vin + (size_t)(b * S + (q0.d * HH + q0.h) * WW + q0.w) * 3);
    F3 g1 = ld3(vin + (size_t)(b * S + (q1.d * HH + q1.h) * WW + q1.w) * 3);

    F3 o0 = {f0.x + g0.x, f0.y + g0.y, f0.z + g0.z};
    F3 o1 = {f1.x + g1.x, f1.y + g1.y, f1.z + g1.z};

    if constexpr (OUT_SOA) {
        int s0 = b * 3 * S + p0, s1 = b * 3 * S + p1;
        vout[s0] = o0.x; vout[s0 + S] = o0.y; vout[s0 + 2 * S] = o0.z;
        vout[s1] = o1.x; vout[s1 + S] = o1.y; vout[s1 + 2 * S] = o1.z;
    } else {
        st3(vout + (size_t)(b * S + p0) * 3, o0);
        st3(vout + (size_t)(b * S + p1) * 3, o1);
    }
}

extern "C" void kernel_launch(void* const* d_in, const int* in_sizes, int n_in,
                              void* d_out, int out_size, void* d_ws, size_t ws_size,
                              hipStream_t stream) {
    const float* x = (const float*)d_in[0];
    float* out = (float*)d_out;
    float* ws  = (float*)d_ws;

    const size_t fieldf = (size_t)BB * S * 3;   // floats per tight AoS field
    float* A = ws;
    // second AoS scratch: ws second half if it fits, else use d_out as scratch
    float* B = (ws_size >= 2 * fieldf * sizeof(float)) ? (ws + fieldf) : out;

    fused3_k      <<<NBLK, 256, 0, stream>>>(x, A);   // steps 1-3 (scale fused)
    step_k<false> <<<NBLK, 256, 0, stream>>>(A, B);   // step 4
    step_k<false> <<<NBLK, 256, 0, stream>>>(B, A);   // step 5
    step_k<true>  <<<NBLK, 256, 0, stream>>>(A, out); // step 6 -> SoA
}

// Round 6
// 309.708 us; speedup vs baseline: 1.0698x; 1.0698x over previous
//
#include <hip/hip_runtime.h>

// x: [B=2, C=3, D=128, H=160, W=160] fp32, num_steps=6
#define BB 2
#define DD 128
#define HH 160
#define WW 160
constexpr int S   = DD * HH * WW;   // voxels per batch = 3,276,800
constexpr int PL  = HH * WW;        // plane = 25,600
constexpr int VPT = 4;              // consecutive voxels per thread (row-aligned: 160 % 4 == 0)
constexpr int VPB = 256 * VPT;      // 1024 voxels per block
constexpr int BPP = PL / VPB;       // 25 blocks per plane
constexpr int NBLK = BB * DD * BPP; // 6400 blocks
constexpr int PER_XCD = NBLK / 8;   // 800 -> contiguous 32-plane slab per XCD

struct I3 { int d, h, w; };

__device__ __forceinline__ I3 warp_coords(int d, int h, int w,
                                          float f0, float f1, float f2) {
    // round-half-to-even (jnp.round == rintf), clamp per-dim
    I3 r;
    r.d = (int)fminf(fmaxf(rintf((float)d + f0), 0.0f), (float)(DD - 1));
    r.h = (int)fminf(fmaxf(rintf((float)h + f1), 0.0f), (float)(HH - 1));
    r.w = (int)fminf(fmaxf(rintf((float)w + f2), 0.0f), (float)(WW - 1));
    return r;
}

// One squaring step, 4 consecutive voxels per thread.
// IN_SOA: vin is [3,S] SoA (input x).  OUT_SOA: vout is [3,S] SoA (d_out).
// Otherwise tight 12 B AoS [S,3].  SCALE folds the initial 1/64 (pass 1 only).
template <bool IN_SOA, bool OUT_SOA, bool SCALE>
__global__ __launch_bounds__(256) void step_k(const float* __restrict__ vin,
                                              float* __restrict__ vout) {
    // XCD-aware swizzle: each XCD owns a contiguous 32-plane slab.
    int bid = blockIdx.x;
    int nb  = (bid >> 3) + (bid & 7) * PER_XCD;
    int b   = nb / (DD * BPP);
    int rr  = nb - b * (DD * BPP);
    int d   = rr / BPP;
    int blk = rr - d * BPP;
    int ip  = blk * VPB + threadIdx.x * VPT;  // 4 consecutive voxels, same row
    int w0  = ip % WW;
    int h   = ip / WW;
    int p   = d * PL + ip;

    const float scale = 1.0f / 64.0f;

    // ---- center loads, fully vectorized ----
    float f[12];  // f[3c+comp] for voxel c
    if constexpr (IN_SOA) {
        const float* xb = vin + b * 3 * S;
        float4 u0 = *(const float4*)(xb + p);
        float4 u1 = *(const float4*)(xb + S + p);
        float4 u2 = *(const float4*)(xb + 2 * S + p);
        f[0]=u0.x; f[3]=u0.y; f[6]=u0.z; f[9] =u0.w;
        f[1]=u1.x; f[4]=u1.y; f[7]=u1.z; f[10]=u1.w;
        f[2]=u2.x; f[5]=u2.y; f[8]=u2.z; f[11]=u2.w;
    } else {
        const float4* src = (const float4*)(vin + (size_t)(b * S + p) * 3);
        float4 a = src[0], c4 = src[1], e = src[2];
        f[0]=a.x; f[1]=a.y; f[2]=a.z;  f[3]=a.w;
        f[4]=c4.x;f[5]=c4.y;f[6]=c4.z; f[7]=c4.w;
        f[8]=e.x; f[9]=e.y; f[10]=e.z; f[11]=e.w;
    }
    if constexpr (SCALE) {
#pragma unroll
        for (int i = 0; i < 12; ++i) f[i] *= scale;
    }

    // ---- warp indices + wave-uniform identity check ----
    I3 q[4];
    bool neq = false;
#pragma unroll
    for (int c = 0; c < 4; ++c) {
        q[c] = warp_coords(d, h, w0 + c, f[3*c], f[3*c+1], f[3*c+2]);
        neq |= (q[c].d != d) | (q[c].h != h) | (q[c].w != (w0 + c));
    }

    float g[12];
    if (__ballot(neq)) {
        // 4 independent gathers (MLP)
#pragma unroll
        for (int c = 0; c < 4; ++c) {
            int qi = (q[c].d * HH + q[c].h) * WW + q[c].w;
            if constexpr (IN_SOA) {
                const float* xb = vin + b * 3 * S;
                g[3*c]   = xb[qi];
                g[3*c+1] = xb[qi + S];
                g[3*c+2] = xb[qi + 2 * S];
            } else {
                const float* sp = vin + (size_t)(b * S + qi) * 3;
                float t[3];
                __builtin_memcpy(t, sp, 12);   // single global_load_dwordx3
                g[3*c] = t[0]; g[3*c+1] = t[1]; g[3*c+2] = t[2];
            }
        }
        if constexpr (SCALE) {
#pragma unroll
            for (int i = 0; i < 12; ++i) g[i] *= scale;
        }
    } else {
        // whole wave maps to identity: gather value == center value (bit-exact)
#pragma unroll
        for (int i = 0; i < 12; ++i) g[i] = f[i];
    }

    float o[12];
#pragma unroll
    for (int i = 0; i < 12; ++i) o[i] = f[i] + g[i];

    // ---- stores, fully vectorized ----
    if constexpr (OUT_SOA) {
        float* ob = vout + b * 3 * S;
        *(float4*)(ob + p)         = make_float4(o[0], o[3], o[6], o[9]);
        *(float4*)(ob + S + p)     = make_float4(o[1], o[4], o[7], o[10]);
        *(float4*)(ob + 2 * S + p) = make_float4(o[2], o[5], o[8], o[11]);
    } else {
        float4* dst = (float4*)(vout + (size_t)(b * S + p) * 3);
        dst[0] = make_float4(o[0], o[1], o[2],  o[3]);
        dst[1] = make_float4(o[4], o[5], o[6],  o[7]);
        dst[2] = make_float4(o[8], o[9], o[10], o[11]);
    }
}

extern "C" void kernel_launch(void* const* d_in, const int* in_sizes, int n_in,
                              void* d_out, int out_size, void* d_ws, size_t ws_size,
                              hipStream_t stream) {
    const float* x = (const float*)d_in[0];
    float* out = (float*)d_out;
    float* ws  = (float*)d_ws;

    const size_t fieldf = (size_t)BB * S * 3;  // floats per tight AoS field
    float* A = ws;
    float* B = (ws_size >= 2 * fieldf * sizeof(float)) ? (ws + fieldf) : out;

    // 6 unfused passes; 1-deep gather chain each. Pass 6 writes SoA d_out.
    step_k<true,  false, true ><<<NBLK, 256, 0, stream>>>(x, A);   // 1 (scale fused)
    step_k<false, false, false><<<NBLK, 256, 0, stream>>>(A, B);   // 2
    step_k<false, false, false><<<NBLK, 256, 0, stream>>>(B, A);   // 3
    step_k<false, false, false><<<NBLK, 256, 0, stream>>>(A, B);   // 4
    step_k<false, false, false><<<NBLK, 256, 0, stream>>>(B, A);   // 5
    step_k<false, true,  false><<<NBLK, 256, 0, stream>>>(A, out); // 6
}